// Round 6
// baseline (3040.193 us; speedup 1.0000x reference)
//
#include <hip/hip_runtime.h>

// ---------------------------------------------------------------------------
// JK-SAGE forward. Bucket-partitioned aggregation (no per-node CSR, no 4B
// scatters), bf16 features, fp32 accumulate, MFMA bf16 GEMMs.
//   per layer: bucket hist -> scan -> LDS-staged partition -> LDS-accum
//              aggregate (mean) -> MFMA GEMM
//   out = h1 @ Wo[:128] + h2 @ Wo[128:] + b_out  (fp32 out)
// Edge record: src | (dst&511)<<17  (requires N <= 131072; here N = 100000).
// ---------------------------------------------------------------------------

#define MAXNB 256    // max buckets (N <= 131072)
#define CAP   48     // partition LDS staging entries per bucket
#define PBLK  384    // partition grid

typedef __attribute__((ext_vector_type(8))) short short8;
typedef __attribute__((ext_vector_type(4))) float floatx4;

__device__ __forceinline__ unsigned short f2b(float f) {
    unsigned u = __float_as_uint(f);
    unsigned r = (u + 0x7fffu + ((u >> 16) & 1u)) >> 16;   // RNE
    return (unsigned short)r;
}
__device__ __forceinline__ float lo2f(unsigned u) { return __uint_as_float(u << 16); }
__device__ __forceinline__ float hi2f(unsigned u) { return __uint_as_float(u & 0xffff0000u); }
__device__ __forceinline__ unsigned pack2(float a, float b) {
    return (unsigned)f2b(a) | ((unsigned)f2b(b) << 16);
}

// ---- one-time x fp32 -> bf16 (8 elems/thread)
__global__ __launch_bounds__(256)
void cast_f32_b16(const float4* __restrict__ src, uint4* __restrict__ dst, long n8) {
    long i = (long)blockIdx.x * 256 + threadIdx.x;
    if (i >= n8) return;
    float4 a = src[i * 2];
    float4 b = src[i * 2 + 1];
    uint4 o;
    o.x = pack2(a.x, a.y); o.y = pack2(a.z, a.w);
    o.z = pack2(b.x, b.y); o.w = pack2(b.z, b.w);
    dst[i] = o;
}

// ---- weight cast + repack into MFMA b-frag order (see round-4 notes).
__global__ __launch_bounds__(256)
void prep_weights(const float* __restrict__ wl1, const float* __restrict__ wr1,
                  const float* __restrict__ wl2, const float* __restrict__ wr2,
                  const float* __restrict__ wo,
                  unsigned short* __restrict__ wt1, unsigned short* __restrict__ wt2,
                  unsigned short* __restrict__ wot) {
    int idx = blockIdx.x * 256 + threadIdx.x;
    if (idx < 65536) {   // two layer matrices, 32768 each
        int l = idx >> 15;
        int i = idx & 32767;
        int j = i & 7, lane = (i >> 3) & 63, kb = (i >> 9) & 7, c = i >> 12;
        int k = kb * 32 + (lane >> 4) * 8 + j;
        int n = c * 16 + (lane & 15);
        const float* Wl = l ? wl2 : wl1;
        const float* Wr = l ? wr2 : wr1;
        float v = (k < 128) ? Wl[k * 128 + n] : Wr[(k - 128) * 128 + n];
        (l ? wt2 : wt1)[i] = f2b(v);
    } else if (idx < 65536 + 12288) {
        int i = idx - 65536;
        int j = i & 7, lane = (i >> 3) & 63, kb = (i >> 9) & 7, c = i >> 12;
        int k = kb * 32 + (lane >> 4) * 8 + j;
        int col = c * 16 + (lane & 15);
        float v = (col < 40) ? wo[k * 40 + col] : 0.0f;
        wot[i] = f2b(v);
    }
}

// ---- per-bucket (512-dst-node) edge histogram, LDS-staged
__global__ __launch_bounds__(256)
void bucket_hist(const int* __restrict__ dst, int* __restrict__ hist, int E, int nb) {
    __shared__ int h[MAXNB];
    for (int i = threadIdx.x; i < nb; i += 256) h[i] = 0;
    __syncthreads();
    for (int e = blockIdx.x * 256 + threadIdx.x; e < E; e += gridDim.x * 256)
        atomicAdd(&h[dst[e] >> 9], 1);
    __syncthreads();
    for (int i = threadIdx.x; i < nb; i += 256)
        if (h[i]) atomicAdd(&hist[i], h[i]);
}

// ---- exclusive scan of bucket counts (single block, nb <= 256)
__global__ __launch_bounds__(256)
void bucket_scan(const int* __restrict__ hist, int* __restrict__ bptr, int nb, int E) {
    __shared__ int lds[256];
    int t = threadIdx.x;
    int v = (t < nb) ? hist[t] : 0;
    lds[t] = v;
    __syncthreads();
    for (int off = 1; off < 256; off <<= 1) {
        int y = (t >= off) ? lds[t - off] : 0;
        __syncthreads();
        lds[t] += y;
        __syncthreads();
    }
    if (t < nb) bptr[t] = lds[t] - v;   // exclusive
    if (t == 0) bptr[nb] = E;
}

// ---- partition edges into bucket regions with LDS chunk staging.
// Each block handles a contiguous edge range, stages records per bucket in
// LDS, flushes ~CAP-entry contiguous chunks via one cursor atomic each.
__global__ __launch_bounds__(256)
void partition_edges(const int* __restrict__ src, const int* __restrict__ dst,
                     const int* __restrict__ bptr, int* __restrict__ gcur,
                     int* __restrict__ part, int E, int nb) {
    __shared__ unsigned stage[MAXNB][CAP];
    __shared__ int lcnt[MAXNB];
    const int t = threadIdx.x;
    for (int i = t; i < nb; i += 256) lcnt[i] = 0;
    __syncthreads();
    const int per = (E + gridDim.x - 1) / gridDim.x;
    const int e0 = blockIdx.x * per;
    const int e1 = min(e0 + per, E);
    for (int e = e0 + t; e < e1; e += 256) {
        int d = dst[e];
        int b = d >> 9;
        unsigned rec = (unsigned)src[e] | ((unsigned)(d & 511) << 17);
        int p = atomicAdd(&lcnt[b], 1);
        if (p < CAP) stage[b][p] = rec;
        else {   // staging overflow (rare): direct global write
            int g = atomicAdd(&gcur[b], 1);
            part[bptr[b] + g] = (int)rec;
        }
    }
    __syncthreads();
    for (int b = t; b < nb; b += 256) {
        int c = lcnt[b]; if (c > CAP) c = CAP;
        if (c > 0) {
            int g = atomicAdd(&gcur[b], c);
            int base = bptr[b] + g;
            for (int i = 0; i < c; ++i) part[base + i] = (int)stage[b][i];
        }
    }
}

// ---- aggregate: mean of neighbor rows per dst node.
// Grid = nb*4: block (b,q) owns bucket b's 512 nodes x feature quarter
// q (32 feats). All records processed (no divergence); 4 records per wave
// iteration (16 lanes each read 64 B of the src row) -> pipelined VMEM.
// fp32 LDS accumulate via ds_add (even/odd feature planes), bf16 out.
__global__ __launch_bounds__(256)
void aggregate_feat(const unsigned* __restrict__ xb32, const int* __restrict__ bptr,
                    const int* __restrict__ part, unsigned* __restrict__ agg32,
                    int N) {
    __shared__ float pA[512][16];   // even feats of quarter
    __shared__ float pB[512][16];   // odd feats
    __shared__ float ldeg[512];

    const int b = blockIdx.x >> 2;
    const int q = blockIdx.x & 3;
    const int t = threadIdx.x;
    const int w = t >> 6;
    const int lane = t & 63;
    const int g  = lane >> 4;       // record sub-group within wave
    const int fl = lane & 15;       // feat-pair lane

    for (int i = t; i < 512 * 16; i += 256) {
        ((float*)pA)[i] = 0.f;
        ((float*)pB)[i] = 0.f;
    }
    for (int i = t; i < 512; i += 256) ldeg[i] = 0.f;
    __syncthreads();

    const int beg = bptr[b], end = bptr[b + 1];
    for (int r = beg + w * 4 + g; r < end; r += 16) {
        unsigned rec = (unsigned)part[r];
        int node = rec >> 17;
        int s    = rec & 0x1FFFF;
        unsigned u = xb32[(size_t)s * 64 + q * 16 + fl];
        atomicAdd(&pA[node][fl], lo2f(u));
        atomicAdd(&pB[node][fl], hi2f(u));
        if (fl == 0) atomicAdd(&ldeg[node], 1.0f);
    }
    __syncthreads();

    const int base512 = b << 9;
    for (int i = t; i < 512 * 16; i += 256) {
        int node = i >> 4, j = i & 15;
        int row = base512 + node;
        if (row < N) {
            float inv = 1.0f / fmaxf(ldeg[node], 1.0f);
            agg32[(size_t)row * 64 + q * 16 + j] =
                pack2(pA[node][j] * inv, pB[node][j] * inv);
        }
    }
}

// H = relu([Agg | X] @ [Wl;Wr] + bias), MFMA 16x16x32 bf16.
// Block: 128 rows, 4 waves; wave = 32 rows x 128 cols. No LDS, no barriers.
__global__ __launch_bounds__(256)
void sage_gemm_mfma(const unsigned short* __restrict__ Aggb,
                    const unsigned short* __restrict__ Xb,
                    const unsigned short* __restrict__ Wt,   // frag-order [8][8][64][8]
                    const float* __restrict__ bias,
                    unsigned short* __restrict__ Hb, int N) {
    const int wave = threadIdx.x >> 6;
    const int lane = threadIdx.x & 63;
    const int quad = lane >> 4;
    const int l16  = lane & 15;
    const int rowbase = blockIdx.x * 128 + wave * 32;

    floatx4 acc[2][8];
#pragma unroll
    for (int r = 0; r < 2; ++r)
#pragma unroll
        for (int c = 0; c < 8; ++c) acc[r][c] = (floatx4){0.f, 0.f, 0.f, 0.f};

    int arow0 = rowbase + l16;      if (arow0 >= N) arow0 = N - 1;
    int arow1 = rowbase + 16 + l16; if (arow1 >= N) arow1 = N - 1;
    const size_t aoff0 = (size_t)arow0 * 128 + quad * 8;
    const size_t aoff1 = (size_t)arow1 * 128 + quad * 8;

#pragma unroll
    for (int kb = 0; kb < 8; ++kb) {
        const unsigned short* Ab = (kb < 4) ? Aggb : Xb;
        const int koff = (kb & 3) * 32;
        short8 a0 = __builtin_bit_cast(short8, *(const uint4*)(Ab + aoff0 + koff));
        short8 a1 = __builtin_bit_cast(short8, *(const uint4*)(Ab + aoff1 + koff));
#pragma unroll
        for (int c = 0; c < 8; ++c) {
            short8 b = __builtin_bit_cast(short8,
                *(const uint4*)(Wt + (size_t)(((c * 8 + kb) * 64 + lane) * 8)));
            acc[0][c] = __builtin_amdgcn_mfma_f32_16x16x32_bf16(a0, b, acc[0][c], 0, 0, 0);
            acc[1][c] = __builtin_amdgcn_mfma_f32_16x16x32_bf16(a1, b, acc[1][c], 0, 0, 0);
        }
    }

    float bcol[8];
#pragma unroll
    for (int c = 0; c < 8; ++c) bcol[c] = bias[c * 16 + l16];
#pragma unroll
    for (int r = 0; r < 2; ++r)
#pragma unroll
        for (int i = 0; i < 4; ++i) {
            int row = rowbase + r * 16 + quad * 4 + i;
            if (row < N) {
#pragma unroll
                for (int c = 0; c < 8; ++c)
                    Hb[(size_t)row * 128 + c * 16 + l16] =
                        f2b(fmaxf(acc[r][c][i] + bcol[c], 0.f));
            }
        }
}

// out = [H1 | H2] @ Wot + b_out (fp32 out, 40 cols via 3 masked tiles).
__global__ __launch_bounds__(256)
void out_gemm_mfma(const unsigned short* __restrict__ H1b,
                   const unsigned short* __restrict__ H2b,
                   const unsigned short* __restrict__ Wot,  // frag-order [3][8][64][8]
                   const float* __restrict__ bo,
                   float* __restrict__ out, int N) {
    const int wave = threadIdx.x >> 6;
    const int lane = threadIdx.x & 63;
    const int quad = lane >> 4;
    const int l16  = lane & 15;
    const int rowbase = blockIdx.x * 128 + wave * 32;

    floatx4 acc[2][3];
#pragma unroll
    for (int r = 0; r < 2; ++r)
#pragma unroll
        for (int c = 0; c < 3; ++c) acc[r][c] = (floatx4){0.f, 0.f, 0.f, 0.f};

    int arow0 = rowbase + l16;      if (arow0 >= N) arow0 = N - 1;
    int arow1 = rowbase + 16 + l16; if (arow1 >= N) arow1 = N - 1;
    const size_t aoff0 = (size_t)arow0 * 128 + quad * 8;
    const size_t aoff1 = (size_t)arow1 * 128 + quad * 8;

#pragma unroll
    for (int kb = 0; kb < 8; ++kb) {
        const unsigned short* Ab = (kb < 4) ? H1b : H2b;
        const int koff = (kb & 3) * 32;
        short8 a0 = __builtin_bit_cast(short8, *(const uint4*)(Ab + aoff0 + koff));
        short8 a1 = __builtin_bit_cast(short8, *(const uint4*)(Ab + aoff1 + koff));
#pragma unroll
        for (int c = 0; c < 3; ++c) {
            short8 b = __builtin_bit_cast(short8,
                *(const uint4*)(Wot + (size_t)(((c * 8 + kb) * 64 + lane) * 8)));
            acc[0][c] = __builtin_amdgcn_mfma_f32_16x16x32_bf16(a0, b, acc[0][c], 0, 0, 0);
            acc[1][c] = __builtin_amdgcn_mfma_f32_16x16x32_bf16(a1, b, acc[1][c], 0, 0, 0);
        }
    }

    float bcol[3];
#pragma unroll
    for (int c = 0; c < 3; ++c) {
        int colc = c * 16 + l16;
        bcol[c] = (colc < 40) ? bo[colc] : 0.f;
    }
#pragma unroll
    for (int r = 0; r < 2; ++r)
#pragma unroll
        for (int i = 0; i < 4; ++i) {
            int row = rowbase + r * 16 + quad * 4 + i;
            if (row < N) {
#pragma unroll
                for (int c = 0; c < 3; ++c) {
                    int colc = c * 16 + l16;
                    if (colc < 40)
                        out[(size_t)row * 40 + colc] = acc[r][c][i] + bcol[c];
                }
            }
        }
}

extern "C" void kernel_launch(void* const* d_in, const int* in_sizes, int n_in,
                              void* d_out, int out_size, void* d_ws, size_t ws_size,
                              hipStream_t stream) {
    const float* x     = (const float*)d_in[0];
    const int*   ei1   = (const int*)d_in[1];
    const int*   ei2   = (const int*)d_in[2];
    const float* wl1   = (const float*)d_in[3];
    const float* wr1   = (const float*)d_in[4];
    const float* b1    = (const float*)d_in[5];
    const float* wl2   = (const float*)d_in[6];
    const float* wr2   = (const float*)d_in[7];
    const float* b2    = (const float*)d_in[8];
    const float* w_out = (const float*)d_in[9];
    const float* b_out = (const float*)d_in[10];

    const int N  = in_sizes[0] / 128;
    const int E  = in_sizes[1] / 2;
    const int nb = (N + 511) >> 9;   // buckets of 512 dst nodes (<= MAXNB)

    // ---- workspace: hist[256] | gcur[256] | bptr[257] | part[E] | bf16 arrays
    int* hist = (int*)d_ws;
    int* gcur = hist + 256;
    int* bptr = gcur + 256;
    int* part = bptr + 257;
    size_t int_cnt = (size_t)(256 + 256 + 257) + (size_t)E;
    int_cnt = (int_cnt + 3) & ~(size_t)3;                 // 16 B align
    unsigned short* xb   = (unsigned short*)((int*)d_ws + int_cnt);
    unsigned short* h1b  = xb  + (size_t)N * 128;
    unsigned short* h2b  = h1b + (size_t)N * 128;
    unsigned short* aggb = h2b + (size_t)N * 128;
    unsigned short* wt1  = aggb + (size_t)N * 128;
    unsigned short* wt2  = wt1 + 32768;
    unsigned short* wot  = wt2 + 32768;

    const long n8         = (long)N * 128 / 8;
    const int cast_blocks = (int)((n8 + 255) / 256);
    const int mfma_blocks = (N + 127) / 128;

    cast_f32_b16<<<cast_blocks, 256, 0, stream>>>((const float4*)x, (uint4*)xb, n8);
    prep_weights<<<(65536 + 12288 + 255) / 256, 256, 0, stream>>>(
        wl1, wr1, wl2, wr2, w_out, wt1, wt2, wot);

    for (int layer = 0; layer < 2; ++layer) {
        const int* ei = (layer == 0) ? ei1 : ei2;
        const unsigned short* xin = (layer == 0) ? xb : h1b;
        const unsigned short* wt  = (layer == 0) ? wt1 : wt2;
        const float* bb = (layer == 0) ? b1 : b2;
        unsigned short* hout = (layer == 0) ? h1b : h2b;
        const int* srcp = ei;
        const int* dstp = ei + E;

        hipMemsetAsync(hist, 0, 512 * sizeof(int), stream);   // hist + gcur
        bucket_hist<<<256, 256, 0, stream>>>(dstp, hist, E, nb);
        bucket_scan<<<1, 256, 0, stream>>>(hist, bptr, nb, E);
        partition_edges<<<PBLK, 256, 0, stream>>>(srcp, dstp, bptr, gcur, part, E, nb);
        aggregate_feat<<<nb * 4, 256, 0, stream>>>((const unsigned*)xin, bptr, part,
                                                   (unsigned*)aggb, N);
        sage_gemm_mfma<<<mfma_blocks, 256, 0, stream>>>(aggb, xin, wt, bb, hout, N);
    }

    out_gemm_mfma<<<mfma_blocks, 256, 0, stream>>>(h1b, h2b, wot, b_out,
                                                   (float*)d_out, N);
}

// Round 7
// 487.295 us; speedup vs baseline: 6.2389x; 6.2389x over previous
//
#include <hip/hip_runtime.h>

// ---------------------------------------------------------------------------
// JK-SAGE forward. bf16 features, fp32 accumulate, MFMA bf16 GEMMs.
// CSR built via bucket sort (no 4B random scatters):
//   bucket_hist -> bucket_scan -> partition (LDS chunk-staged) ->
//   node_sort (per-bucket LDS counting sort, coalesced writes) ->
//   gather_mean (per-node, 16 lanes) -> MFMA GEMM
//   out = h1 @ Wo[:128] + h2 @ Wo[128:] + b_out  (fp32 out)
// Edge record: src | (dst&255)<<17  (requires N <= 131072; here N = 100000).
// ---------------------------------------------------------------------------

#define MAXB  512    // max buckets (N <= 131072 with 256-node buckets)
#define CAP   24     // partition LDS staging entries per bucket
#define CAPS  6144   // node_sort per-bucket record capacity (lambda=4096, 32 sigma)
#define PBLK  384    // partition grid

typedef __attribute__((ext_vector_type(8))) short short8;
typedef __attribute__((ext_vector_type(4))) float floatx4;

__device__ __forceinline__ unsigned short f2b(float f) {
    unsigned u = __float_as_uint(f);
    unsigned r = (u + 0x7fffu + ((u >> 16) & 1u)) >> 16;   // RNE
    return (unsigned short)r;
}
__device__ __forceinline__ float lo2f(unsigned u) { return __uint_as_float(u << 16); }
__device__ __forceinline__ float hi2f(unsigned u) { return __uint_as_float(u & 0xffff0000u); }
__device__ __forceinline__ unsigned pack2(float a, float b) {
    return (unsigned)f2b(a) | ((unsigned)f2b(b) << 16);
}

// ---- one-time x fp32 -> bf16 (8 elems/thread)
__global__ __launch_bounds__(256)
void cast_f32_b16(const float4* __restrict__ src, uint4* __restrict__ dst, long n8) {
    long i = (long)blockIdx.x * 256 + threadIdx.x;
    if (i >= n8) return;
    float4 a = src[i * 2];
    float4 b = src[i * 2 + 1];
    uint4 o;
    o.x = pack2(a.x, a.y); o.y = pack2(a.z, a.w);
    o.z = pack2(b.x, b.y); o.w = pack2(b.z, b.w);
    dst[i] = o;
}

// ---- weight cast + repack into MFMA b-frag order (see round-4 notes).
__global__ __launch_bounds__(256)
void prep_weights(const float* __restrict__ wl1, const float* __restrict__ wr1,
                  const float* __restrict__ wl2, const float* __restrict__ wr2,
                  const float* __restrict__ wo,
                  unsigned short* __restrict__ wt1, unsigned short* __restrict__ wt2,
                  unsigned short* __restrict__ wot) {
    int idx = blockIdx.x * 256 + threadIdx.x;
    if (idx < 65536) {   // two layer matrices, 32768 each
        int l = idx >> 15;
        int i = idx & 32767;
        int j = i & 7, lane = (i >> 3) & 63, kb = (i >> 9) & 7, c = i >> 12;
        int k = kb * 32 + (lane >> 4) * 8 + j;
        int n = c * 16 + (lane & 15);
        const float* Wl = l ? wl2 : wl1;
        const float* Wr = l ? wr2 : wr1;
        float v = (k < 128) ? Wl[k * 128 + n] : Wr[(k - 128) * 128 + n];
        (l ? wt2 : wt1)[i] = f2b(v);
    } else if (idx < 65536 + 12288) {
        int i = idx - 65536;
        int j = i & 7, lane = (i >> 3) & 63, kb = (i >> 9) & 7, c = i >> 12;
        int k = kb * 32 + (lane >> 4) * 8 + j;
        int col = c * 16 + (lane & 15);
        float v = (col < 40) ? wo[k * 40 + col] : 0.0f;
        wot[i] = f2b(v);
    }
}

// ---- per-bucket (256-dst-node) edge histogram, LDS-staged
__global__ __launch_bounds__(256)
void bucket_hist(const int* __restrict__ dst, int* __restrict__ hist, int E, int nb) {
    __shared__ int h[MAXB];
    for (int i = threadIdx.x; i < nb; i += 256) h[i] = 0;
    __syncthreads();
    for (int e = blockIdx.x * 256 + threadIdx.x; e < E; e += gridDim.x * 256)
        atomicAdd(&h[dst[e] >> 8], 1);
    __syncthreads();
    for (int i = threadIdx.x; i < nb; i += 256)
        if (h[i]) atomicAdd(&hist[i], h[i]);
}

// ---- exclusive scan of bucket counts (single block, nb <= 512)
__global__ __launch_bounds__(256)
void bucket_scan(const int* __restrict__ hist, int* __restrict__ bptr, int nb, int E) {
    __shared__ int pair[256];
    int t = threadIdx.x;
    int v0 = (2 * t < nb) ? hist[2 * t] : 0;
    int v1 = (2 * t + 1 < nb) ? hist[2 * t + 1] : 0;
    pair[t] = v0 + v1;
    __syncthreads();
    for (int off = 1; off < 256; off <<= 1) {
        int y = (t >= off) ? pair[t - off] : 0;
        __syncthreads();
        pair[t] += y;
        __syncthreads();
    }
    int ebase = pair[t] - (v0 + v1);   // exclusive pair prefix
    if (2 * t < nb)     bptr[2 * t]     = ebase;
    if (2 * t + 1 < nb) bptr[2 * t + 1] = ebase + v0;
    if (t == 0) bptr[nb] = E;
}

// ---- partition edges into bucket regions with LDS chunk staging.
__global__ __launch_bounds__(256)
void partition_edges(const int* __restrict__ src, const int* __restrict__ dst,
                     const int* __restrict__ bptr, int* __restrict__ gcur,
                     int* __restrict__ part, int E, int nb) {
    __shared__ unsigned stage[MAXB][CAP];
    __shared__ int lcnt[MAXB];
    const int t = threadIdx.x;
    for (int i = t; i < nb; i += 256) lcnt[i] = 0;
    __syncthreads();
    const int per = (E + gridDim.x - 1) / gridDim.x;
    const int e0 = blockIdx.x * per;
    const int e1 = min(e0 + per, E);
    for (int e = e0 + t; e < e1; e += 256) {
        int d = dst[e];
        int b = d >> 8;
        unsigned rec = (unsigned)src[e] | ((unsigned)(d & 255) << 17);
        int p = atomicAdd(&lcnt[b], 1);
        if (p < CAP) stage[b][p] = rec;
        else {   // staging overflow (rare): direct global write
            int g = atomicAdd(&gcur[b], 1);
            part[bptr[b] + g] = (int)rec;
        }
    }
    __syncthreads();
    for (int b = t; b < nb; b += 256) {
        int c = lcnt[b]; if (c > CAP) c = CAP;
        if (c > 0) {
            int g = atomicAdd(&gcur[b], c);
            int base = bptr[b] + g;
            for (int i = 0; i < c; ++i) part[base + i] = (int)stage[b][i];
        }
    }
}

// ---- per-bucket counting sort: records -> per-node CSR order.
// One block per bucket. All loads/stores coalesced; scatter only inside LDS.
// Emits row_ptr (global) and col (src indices, node-sorted).
__global__ __launch_bounds__(256)
void node_sort(const int* __restrict__ bptr, const int* __restrict__ part,
               int* __restrict__ col, int* __restrict__ row_ptr, int N, int E) {
    __shared__ int recs[CAPS];
    __shared__ int sorted[CAPS];
    __shared__ int hcnt[256];
    __shared__ int hoff[256];
    const int b = blockIdx.x, t = threadIdx.x;
    const int beg = bptr[b], end = bptr[b + 1];
    int cnt = end - beg;
    if (cnt > CAPS) cnt = CAPS;   // statistically impossible (32 sigma margin)

    for (int i = t; i < cnt; i += 256) recs[i] = part[beg + i];
    hcnt[t] = 0;
    __syncthreads();
    for (int i = t; i < cnt; i += 256)
        atomicAdd(&hcnt[((unsigned)recs[i]) >> 17], 1);
    __syncthreads();

    // exclusive scan of hcnt
    int v = hcnt[t];
    hoff[t] = v;
    __syncthreads();
    for (int off = 1; off < 256; off <<= 1) {
        int y = (t >= off) ? hoff[t - off] : 0;
        __syncthreads();
        hoff[t] += y;
        __syncthreads();
    }
    int myoff = hoff[t] - v;   // exclusive prefix for local node t

    int row = b * 256 + t;
    if (row <= N) row_ptr[row] = beg + myoff;
    if (b == gridDim.x - 1 && t == 0) row_ptr[N] = E;   // boundary safety
    __syncthreads();
    hoff[t] = myoff;   // now exclusive
    hcnt[t] = 0;       // reuse as cursor
    __syncthreads();

    for (int i = t; i < cnt; i += 256) {
        unsigned rec = (unsigned)recs[i];
        int node = rec >> 17;
        int p = hoff[node] + atomicAdd(&hcnt[node], 1);
        sorted[p] = (int)(rec & 0x1FFFF);
    }
    __syncthreads();
    for (int i = t; i < cnt; i += 256) col[beg + i] = sorted[i];
}

// agg[n] = mean of xb[col[...]] ; bf16 rows (16 uint4/row), 16 lanes/node.
__global__ __launch_bounds__(256)
void gather_mean_b16(const uint4* __restrict__ xb, const int* __restrict__ row_ptr,
                     const int* __restrict__ col, uint4* __restrict__ agg, int N) {
    int gid  = blockIdx.x * 256 + threadIdx.x;
    int node = gid >> 4;
    int lane = gid & 15;
    if (node >= N) return;
    int beg = row_ptr[node], end = row_ptr[node + 1];
    float acc[8];
#pragma unroll
    for (int j = 0; j < 8; ++j) acc[j] = 0.0f;
    int e = beg;
    for (; e + 3 < end; e += 4) {
        int s0 = col[e], s1 = col[e + 1], s2 = col[e + 2], s3 = col[e + 3];
        uint4 v0 = xb[(size_t)s0 * 16 + lane];
        uint4 v1 = xb[(size_t)s1 * 16 + lane];
        uint4 v2 = xb[(size_t)s2 * 16 + lane];
        uint4 v3 = xb[(size_t)s3 * 16 + lane];
        acc[0] += (lo2f(v0.x) + lo2f(v1.x)) + (lo2f(v2.x) + lo2f(v3.x));
        acc[1] += (hi2f(v0.x) + hi2f(v1.x)) + (hi2f(v2.x) + hi2f(v3.x));
        acc[2] += (lo2f(v0.y) + lo2f(v1.y)) + (lo2f(v2.y) + lo2f(v3.y));
        acc[3] += (hi2f(v0.y) + hi2f(v1.y)) + (hi2f(v2.y) + hi2f(v3.y));
        acc[4] += (lo2f(v0.z) + lo2f(v1.z)) + (lo2f(v2.z) + lo2f(v3.z));
        acc[5] += (hi2f(v0.z) + hi2f(v1.z)) + (hi2f(v2.z) + hi2f(v3.z));
        acc[6] += (lo2f(v0.w) + lo2f(v1.w)) + (lo2f(v2.w) + lo2f(v3.w));
        acc[7] += (hi2f(v0.w) + hi2f(v1.w)) + (hi2f(v2.w) + hi2f(v3.w));
    }
    for (; e < end; ++e) {
        uint4 v0 = xb[(size_t)col[e] * 16 + lane];
        acc[0] += lo2f(v0.x); acc[1] += hi2f(v0.x);
        acc[2] += lo2f(v0.y); acc[3] += hi2f(v0.y);
        acc[4] += lo2f(v0.z); acc[5] += hi2f(v0.z);
        acc[6] += lo2f(v0.w); acc[7] += hi2f(v0.w);
    }
    float inv = 1.0f / fmaxf((float)(end - beg), 1.0f);
#pragma unroll
    for (int j = 0; j < 8; ++j) acc[j] *= inv;
    uint4 o;
    o.x = pack2(acc[0], acc[1]); o.y = pack2(acc[2], acc[3]);
    o.z = pack2(acc[4], acc[5]); o.w = pack2(acc[6], acc[7]);
    agg[(size_t)node * 16 + lane] = o;
}

// H = relu([Agg | X] @ [Wl;Wr] + bias), MFMA 16x16x32 bf16.
// Block: 128 rows, 4 waves; wave = 32 rows x 128 cols. No LDS, no barriers.
__global__ __launch_bounds__(256)
void sage_gemm_mfma(const unsigned short* __restrict__ Aggb,
                    const unsigned short* __restrict__ Xb,
                    const unsigned short* __restrict__ Wt,   // frag-order [8][8][64][8]
                    const float* __restrict__ bias,
                    unsigned short* __restrict__ Hb, int N) {
    const int wave = threadIdx.x >> 6;
    const int lane = threadIdx.x & 63;
    const int quad = lane >> 4;
    const int l16  = lane & 15;
    const int rowbase = blockIdx.x * 128 + wave * 32;

    floatx4 acc[2][8];
#pragma unroll
    for (int r = 0; r < 2; ++r)
#pragma unroll
        for (int c = 0; c < 8; ++c) acc[r][c] = (floatx4){0.f, 0.f, 0.f, 0.f};

    int arow0 = rowbase + l16;      if (arow0 >= N) arow0 = N - 1;
    int arow1 = rowbase + 16 + l16; if (arow1 >= N) arow1 = N - 1;
    const size_t aoff0 = (size_t)arow0 * 128 + quad * 8;
    const size_t aoff1 = (size_t)arow1 * 128 + quad * 8;

#pragma unroll
    for (int kb = 0; kb < 8; ++kb) {
        const unsigned short* Ab = (kb < 4) ? Aggb : Xb;
        const int koff = (kb & 3) * 32;
        short8 a0 = __builtin_bit_cast(short8, *(const uint4*)(Ab + aoff0 + koff));
        short8 a1 = __builtin_bit_cast(short8, *(const uint4*)(Ab + aoff1 + koff));
#pragma unroll
        for (int c = 0; c < 8; ++c) {
            short8 b = __builtin_bit_cast(short8,
                *(const uint4*)(Wt + (size_t)(((c * 8 + kb) * 64 + lane) * 8)));
            acc[0][c] = __builtin_amdgcn_mfma_f32_16x16x32_bf16(a0, b, acc[0][c], 0, 0, 0);
            acc[1][c] = __builtin_amdgcn_mfma_f32_16x16x32_bf16(a1, b, acc[1][c], 0, 0, 0);
        }
    }

    float bcol[8];
#pragma unroll
    for (int c = 0; c < 8; ++c) bcol[c] = bias[c * 16 + l16];
#pragma unroll
    for (int r = 0; r < 2; ++r)
#pragma unroll
        for (int i = 0; i < 4; ++i) {
            int row = rowbase + r * 16 + quad * 4 + i;
            if (row < N) {
#pragma unroll
                for (int c = 0; c < 8; ++c)
                    Hb[(size_t)row * 128 + c * 16 + l16] =
                        f2b(fmaxf(acc[r][c][i] + bcol[c], 0.f));
            }
        }
}

// out = [H1 | H2] @ Wot + b_out (fp32 out, 40 cols via 3 masked tiles).
__global__ __launch_bounds__(256)
void out_gemm_mfma(const unsigned short* __restrict__ H1b,
                   const unsigned short* __restrict__ H2b,
                   const unsigned short* __restrict__ Wot,  // frag-order [3][8][64][8]
                   const float* __restrict__ bo,
                   float* __restrict__ out, int N) {
    const int wave = threadIdx.x >> 6;
    const int lane = threadIdx.x & 63;
    const int quad = lane >> 4;
    const int l16  = lane & 15;
    const int rowbase = blockIdx.x * 128 + wave * 32;

    floatx4 acc[2][3];
#pragma unroll
    for (int r = 0; r < 2; ++r)
#pragma unroll
        for (int c = 0; c < 3; ++c) acc[r][c] = (floatx4){0.f, 0.f, 0.f, 0.f};

    int arow0 = rowbase + l16;      if (arow0 >= N) arow0 = N - 1;
    int arow1 = rowbase + 16 + l16; if (arow1 >= N) arow1 = N - 1;
    const size_t aoff0 = (size_t)arow0 * 128 + quad * 8;
    const size_t aoff1 = (size_t)arow1 * 128 + quad * 8;

#pragma unroll
    for (int kb = 0; kb < 8; ++kb) {
        const unsigned short* Ab = (kb < 4) ? H1b : H2b;
        const int koff = (kb & 3) * 32;
        short8 a0 = __builtin_bit_cast(short8, *(const uint4*)(Ab + aoff0 + koff));
        short8 a1 = __builtin_bit_cast(short8, *(const uint4*)(Ab + aoff1 + koff));
#pragma unroll
        for (int c = 0; c < 3; ++c) {
            short8 b = __builtin_bit_cast(short8,
                *(const uint4*)(Wot + (size_t)(((c * 8 + kb) * 64 + lane) * 8)));
            acc[0][c] = __builtin_amdgcn_mfma_f32_16x16x32_bf16(a0, b, acc[0][c], 0, 0, 0);
            acc[1][c] = __builtin_amdgcn_mfma_f32_16x16x32_bf16(a1, b, acc[1][c], 0, 0, 0);
        }
    }

    float bcol[3];
#pragma unroll
    for (int c = 0; c < 3; ++c) {
        int colc = c * 16 + l16;
        bcol[c] = (colc < 40) ? bo[colc] : 0.f;
    }
#pragma unroll
    for (int r = 0; r < 2; ++r)
#pragma unroll
        for (int i = 0; i < 4; ++i) {
            int row = rowbase + r * 16 + quad * 4 + i;
            if (row < N) {
#pragma unroll
                for (int c = 0; c < 3; ++c) {
                    int colc = c * 16 + l16;
                    if (colc < 40)
                        out[(size_t)row * 40 + colc] = acc[r][c][i] + bcol[c];
                }
            }
        }
}

extern "C" void kernel_launch(void* const* d_in, const int* in_sizes, int n_in,
                              void* d_out, int out_size, void* d_ws, size_t ws_size,
                              hipStream_t stream) {
    const float* x     = (const float*)d_in[0];
    const int*   ei1   = (const int*)d_in[1];
    const int*   ei2   = (const int*)d_in[2];
    const float* wl1   = (const float*)d_in[3];
    const float* wr1   = (const float*)d_in[4];
    const float* b1    = (const float*)d_in[5];
    const float* wl2   = (const float*)d_in[6];
    const float* wr2   = (const float*)d_in[7];
    const float* b2    = (const float*)d_in[8];
    const float* w_out = (const float*)d_in[9];
    const float* b_out = (const float*)d_in[10];

    const int N  = in_sizes[0] / 128;
    const int E  = in_sizes[1] / 2;
    const int nb = (N + 255) >> 8;   // buckets of 256 dst nodes (<= MAXB)

    // ---- workspace: hist[512]|gcur[512]|bptr[513]|row_ptr[N+1]|part[E]|col[E]
    int* hist    = (int*)d_ws;
    int* gcur    = hist + 512;
    int* bptr    = gcur + 512;
    int* row_ptr = bptr + 513;
    int* part    = row_ptr + (N + 1);
    int* col     = part + E;
    size_t int_cnt = (size_t)(512 + 512 + 513 + N + 1) + (size_t)2 * E;
    int_cnt = (int_cnt + 3) & ~(size_t)3;                 // 16 B align
    unsigned short* xb   = (unsigned short*)((int*)d_ws + int_cnt);
    unsigned short* h1b  = xb  + (size_t)N * 128;
    unsigned short* h2b  = h1b + (size_t)N * 128;
    unsigned short* aggb = h2b + (size_t)N * 128;
    unsigned short* wt1  = aggb + (size_t)N * 128;
    unsigned short* wt2  = wt1 + 32768;
    unsigned short* wot  = wt2 + 32768;

    const long n8         = (long)N * 128 / 8;
    const int cast_blocks = (int)((n8 + 255) / 256);
    const int gath_blocks = (int)(((size_t)N * 16 + 255) / 256);
    const int mfma_blocks = (N + 127) / 128;

    cast_f32_b16<<<cast_blocks, 256, 0, stream>>>((const float4*)x, (uint4*)xb, n8);
    prep_weights<<<(65536 + 12288 + 255) / 256, 256, 0, stream>>>(
        wl1, wr1, wl2, wr2, w_out, wt1, wt2, wot);

    for (int layer = 0; layer < 2; ++layer) {
        const int* ei = (layer == 0) ? ei1 : ei2;
        const unsigned short* xin = (layer == 0) ? xb : h1b;
        const unsigned short* wt  = (layer == 0) ? wt1 : wt2;
        const float* bb = (layer == 0) ? b1 : b2;
        unsigned short* hout = (layer == 0) ? h1b : h2b;
        const int* srcp = ei;
        const int* dstp = ei + E;

        hipMemsetAsync(hist, 0, 1024 * sizeof(int), stream);   // hist + gcur
        bucket_hist<<<256, 256, 0, stream>>>(dstp, hist, E, nb);
        bucket_scan<<<1, 256, 0, stream>>>(hist, bptr, nb, E);
        partition_edges<<<PBLK, 256, 0, stream>>>(srcp, dstp, bptr, gcur, part, E, nb);
        node_sort<<<nb, 256, 0, stream>>>(bptr, part, col, row_ptr, N, E);
        gather_mean_b16<<<gath_blocks, 256, 0, stream>>>((const uint4*)xin, row_ptr,
                                                         col, (uint4*)aggb, N);
        sage_gemm_mfma<<<mfma_blocks, 256, 0, stream>>>(aggb, xin, wt, bb, hout, N);
    }

    out_gemm_mfma<<<mfma_blocks, 256, 0, stream>>>(h1b, h2b, wot, b_out,
                                                   (float*)d_out, N);
}

// Round 8
// 443.404 us; speedup vs baseline: 6.8565x; 1.0990x over previous
//
#include <hip/hip_runtime.h>

// ---------------------------------------------------------------------------
// JK-SAGE forward. bf16 features, fp32 accumulate, MFMA bf16 GEMMs.
// Both layers' CSR builds are input-independent -> dual-layer kernels
// (blockIdx.y = layer), 10 dispatches total:
//   prep_all (cast + weight repack + counter zero)
//   bucket_hist2 / bucket_scan2 / partition_edges2 / node_sort2  (x1 each)
//   gather_mean L1, sage_gemm L1, gather_mean L2, sage_gemm L2, out_gemm
// Edge record: src | (dst&255)<<17  (requires N <= 131072; here N = 100000).
// ---------------------------------------------------------------------------

#define MAXB  512    // max buckets (N <= 131072 with 256-node buckets)
#define CAP   24     // partition LDS staging entries per bucket
#define CAPS  6144   // node_sort per-bucket record capacity (lambda=4096, 32 sigma)
#define PBLK  384    // partition grid (per layer)

typedef __attribute__((ext_vector_type(8))) short short8;
typedef __attribute__((ext_vector_type(4))) float floatx4;

__device__ __forceinline__ unsigned short f2b(float f) {
    unsigned u = __float_as_uint(f);
    unsigned r = (u + 0x7fffu + ((u >> 16) & 1u)) >> 16;   // RNE
    return (unsigned short)r;
}
__device__ __forceinline__ float lo2f(unsigned u) { return __uint_as_float(u << 16); }
__device__ __forceinline__ float hi2f(unsigned u) { return __uint_as_float(u & 0xffff0000u); }
__device__ __forceinline__ unsigned pack2(float a, float b) {
    return (unsigned)f2b(a) | ((unsigned)f2b(b) << 16);
}

// ---- fused one-time prep: zero counters, cast x -> bf16, repack weights
__global__ __launch_bounds__(256)
void prep_all(const float4* __restrict__ x4, uint4* __restrict__ xb4, long n8,
              const float* __restrict__ wl1, const float* __restrict__ wr1,
              const float* __restrict__ wl2, const float* __restrict__ wr2,
              const float* __restrict__ wo,
              unsigned short* __restrict__ wt1, unsigned short* __restrict__ wt2,
              unsigned short* __restrict__ wot, int* __restrict__ zero_region) {
    long i = (long)blockIdx.x * 256 + threadIdx.x;
    if (i < 2048) zero_region[i] = 0;                    // hist+gcur, both layers
    if (i < n8) {                                        // cast 8 floats -> bf16
        float4 a = x4[i * 2];
        float4 b = x4[i * 2 + 1];
        uint4 o;
        o.x = pack2(a.x, a.y); o.y = pack2(a.z, a.w);
        o.z = pack2(b.x, b.y); o.w = pack2(b.z, b.w);
        xb4[i] = o;
    }
    if (i < 65536) {   // layer weights into MFMA b-frag order
        int l = (int)(i >> 15);
        int k5 = (int)(i & 32767);
        int j = k5 & 7, lane = (k5 >> 3) & 63, kb = (k5 >> 9) & 7, c = k5 >> 12;
        int k = kb * 32 + (lane >> 4) * 8 + j;
        int n = c * 16 + (lane & 15);
        const float* Wl = l ? wl2 : wl1;
        const float* Wr = l ? wr2 : wr1;
        float v = (k < 128) ? Wl[k * 128 + n] : Wr[(k - 128) * 128 + n];
        (l ? wt2 : wt1)[k5] = f2b(v);
    } else if (i < 65536 + 12288) {
        int k5 = (int)(i - 65536);
        int j = k5 & 7, lane = (k5 >> 3) & 63, kb = (k5 >> 9) & 7, c = k5 >> 12;
        int k = kb * 32 + (lane >> 4) * 8 + j;
        int col = c * 16 + (lane & 15);
        float v = (col < 40) ? wo[k * 40 + col] : 0.0f;
        wot[k5] = f2b(v);
    }
}

// ---- per-bucket (256-dst-node) edge histogram, both layers (blockIdx.y)
__global__ __launch_bounds__(256)
void bucket_hist2(const int* __restrict__ dst1, const int* __restrict__ dst2,
                  int* __restrict__ hist1, int* __restrict__ hist2, int E, int nb) {
    __shared__ int h[MAXB];
    const int* dst = blockIdx.y ? dst2 : dst1;
    int* hist      = blockIdx.y ? hist2 : hist1;
    for (int i = threadIdx.x; i < nb; i += 256) h[i] = 0;
    __syncthreads();
    for (int e = blockIdx.x * 256 + threadIdx.x; e < E; e += gridDim.x * 256)
        atomicAdd(&h[dst[e] >> 8], 1);
    __syncthreads();
    for (int i = threadIdx.x; i < nb; i += 256)
        if (h[i]) atomicAdd(&hist[i], h[i]);
}

// ---- exclusive scan of bucket counts; blockIdx.x = layer
__global__ __launch_bounds__(256)
void bucket_scan2(const int* __restrict__ hist1, const int* __restrict__ hist2,
                  int* __restrict__ bptr1, int* __restrict__ bptr2, int nb, int E) {
    __shared__ int pair[256];
    const int* hist = blockIdx.x ? hist2 : hist1;
    int* bptr       = blockIdx.x ? bptr2 : bptr1;
    int t = threadIdx.x;
    int v0 = (2 * t < nb) ? hist[2 * t] : 0;
    int v1 = (2 * t + 1 < nb) ? hist[2 * t + 1] : 0;
    pair[t] = v0 + v1;
    __syncthreads();
    for (int off = 1; off < 256; off <<= 1) {
        int y = (t >= off) ? pair[t - off] : 0;
        __syncthreads();
        pair[t] += y;
        __syncthreads();
    }
    int ebase = pair[t] - (v0 + v1);
    if (2 * t < nb)     bptr[2 * t]     = ebase;
    if (2 * t + 1 < nb) bptr[2 * t + 1] = ebase + v0;
    if (t == 0) bptr[nb] = E;
}

// ---- partition edges into bucket regions with LDS chunk staging; dual layer
__global__ __launch_bounds__(256)
void partition_edges2(const int* __restrict__ ei1, const int* __restrict__ ei2,
                      const int* __restrict__ bptr1, const int* __restrict__ bptr2,
                      int* __restrict__ gcur1, int* __restrict__ gcur2,
                      int* __restrict__ part1, int* __restrict__ part2,
                      int E, int nb) {
    __shared__ unsigned stage[MAXB][CAP];
    __shared__ int lcnt[MAXB];
    const int* src  = blockIdx.y ? ei2 : ei1;
    const int* dst  = src + E;
    const int* bptr = blockIdx.y ? bptr2 : bptr1;
    int* gcur       = blockIdx.y ? gcur2 : gcur1;
    int* part       = blockIdx.y ? part2 : part1;
    const int t = threadIdx.x;
    for (int i = t; i < nb; i += 256) lcnt[i] = 0;
    __syncthreads();
    const int per = (E + gridDim.x - 1) / gridDim.x;
    const int e0 = blockIdx.x * per;
    const int e1 = min(e0 + per, E);
    for (int e = e0 + t; e < e1; e += 256) {
        int d = dst[e];
        int b = d >> 8;
        unsigned rec = (unsigned)src[e] | ((unsigned)(d & 255) << 17);
        int p = atomicAdd(&lcnt[b], 1);
        if (p < CAP) stage[b][p] = rec;
        else {   // staging overflow (rare): direct global write
            int g = atomicAdd(&gcur[b], 1);
            part[bptr[b] + g] = (int)rec;
        }
    }
    __syncthreads();
    for (int b = t; b < nb; b += 256) {
        int c = lcnt[b]; if (c > CAP) c = CAP;
        if (c > 0) {
            int g = atomicAdd(&gcur[b], c);
            int base = bptr[b] + g;
            for (int i = 0; i < c; ++i) part[base + i] = (int)stage[b][i];
        }
    }
}

// ---- per-bucket counting sort -> per-node CSR order; dual layer
__global__ __launch_bounds__(256)
void node_sort2(const int* __restrict__ bptr1, const int* __restrict__ bptr2,
                const int* __restrict__ part1, const int* __restrict__ part2,
                int* __restrict__ col1, int* __restrict__ col2,
                int* __restrict__ row_ptr1, int* __restrict__ row_ptr2,
                int N, int E) {
    __shared__ int recs[CAPS];
    __shared__ int sorted[CAPS];
    __shared__ int hcnt[256];
    __shared__ int hoff[256];
    const int* bptr = blockIdx.y ? bptr2 : bptr1;
    const int* part = blockIdx.y ? part2 : part1;
    int* col        = blockIdx.y ? col2 : col1;
    int* row_ptr    = blockIdx.y ? row_ptr2 : row_ptr1;
    const int b = blockIdx.x, t = threadIdx.x;
    const int beg = bptr[b], end = bptr[b + 1];
    int cnt = end - beg;
    if (cnt > CAPS) cnt = CAPS;   // statistically impossible (32 sigma margin)

    for (int i = t; i < cnt; i += 256) recs[i] = part[beg + i];
    hcnt[t] = 0;
    __syncthreads();
    for (int i = t; i < cnt; i += 256)
        atomicAdd(&hcnt[((unsigned)recs[i]) >> 17], 1);
    __syncthreads();

    int v = hcnt[t];
    hoff[t] = v;
    __syncthreads();
    for (int off = 1; off < 256; off <<= 1) {
        int y = (t >= off) ? hoff[t - off] : 0;
        __syncthreads();
        hoff[t] += y;
        __syncthreads();
    }
    int myoff = hoff[t] - v;   // exclusive prefix for local node t

    int row = b * 256 + t;
    if (row <= N) row_ptr[row] = beg + myoff;
    if (b == gridDim.x - 1 && t == 0) row_ptr[N] = E;
    __syncthreads();
    hoff[t] = myoff;
    hcnt[t] = 0;       // reuse as cursor
    __syncthreads();

    for (int i = t; i < cnt; i += 256) {
        unsigned rec = (unsigned)recs[i];
        int node = rec >> 17;
        int p = hoff[node] + atomicAdd(&hcnt[node], 1);
        sorted[p] = (int)(rec & 0x1FFFF);
    }
    __syncthreads();
    for (int i = t; i < cnt; i += 256) col[beg + i] = sorted[i];
}

// agg[n] = mean of xb[col[...]] ; bf16 rows (16 uint4/row), 16 lanes/node,
// 8 loads in flight per lane.
__global__ __launch_bounds__(256)
void gather_mean_b16(const uint4* __restrict__ xb, const int* __restrict__ row_ptr,
                     const int* __restrict__ col, uint4* __restrict__ agg, int N) {
    int gid  = blockIdx.x * 256 + threadIdx.x;
    int node = gid >> 4;
    int lane = gid & 15;
    if (node >= N) return;
    int beg = row_ptr[node], end = row_ptr[node + 1];
    float acc[8];
#pragma unroll
    for (int j = 0; j < 8; ++j) acc[j] = 0.0f;
    int e = beg;
    for (; e + 7 < end; e += 8) {   // 8 independent loads in flight
        uint4 v[8];
#pragma unroll
        for (int q = 0; q < 8; ++q) v[q] = xb[(size_t)col[e + q] * 16 + lane];
#pragma unroll
        for (int q = 0; q < 8; ++q) {
            acc[0] += lo2f(v[q].x); acc[1] += hi2f(v[q].x);
            acc[2] += lo2f(v[q].y); acc[3] += hi2f(v[q].y);
            acc[4] += lo2f(v[q].z); acc[5] += hi2f(v[q].z);
            acc[6] += lo2f(v[q].w); acc[7] += hi2f(v[q].w);
        }
    }
    for (; e + 3 < end; e += 4) {
        uint4 v[4];
#pragma unroll
        for (int q = 0; q < 4; ++q) v[q] = xb[(size_t)col[e + q] * 16 + lane];
#pragma unroll
        for (int q = 0; q < 4; ++q) {
            acc[0] += lo2f(v[q].x); acc[1] += hi2f(v[q].x);
            acc[2] += lo2f(v[q].y); acc[3] += hi2f(v[q].y);
            acc[4] += lo2f(v[q].z); acc[5] += hi2f(v[q].z);
            acc[6] += lo2f(v[q].w); acc[7] += hi2f(v[q].w);
        }
    }
    for (; e < end; ++e) {
        uint4 v0 = xb[(size_t)col[e] * 16 + lane];
        acc[0] += lo2f(v0.x); acc[1] += hi2f(v0.x);
        acc[2] += lo2f(v0.y); acc[3] += hi2f(v0.y);
        acc[4] += lo2f(v0.z); acc[5] += hi2f(v0.z);
        acc[6] += lo2f(v0.w); acc[7] += hi2f(v0.w);
    }
    float inv = 1.0f / fmaxf((float)(end - beg), 1.0f);
#pragma unroll
    for (int j = 0; j < 8; ++j) acc[j] *= inv;
    uint4 o;
    o.x = pack2(acc[0], acc[1]); o.y = pack2(acc[2], acc[3]);
    o.z = pack2(acc[4], acc[5]); o.w = pack2(acc[6], acc[7]);
    agg[(size_t)node * 16 + lane] = o;
}

// H = relu([Agg | X] @ [Wl;Wr] + bias), MFMA 16x16x32 bf16.
// Block: 128 rows, 4 waves; wave = 32 rows x 128 cols. No LDS, no barriers.
__global__ __launch_bounds__(256)
void sage_gemm_mfma(const unsigned short* __restrict__ Aggb,
                    const unsigned short* __restrict__ Xb,
                    const unsigned short* __restrict__ Wt,   // frag-order [8][8][64][8]
                    const float* __restrict__ bias,
                    unsigned short* __restrict__ Hb, int N) {
    const int wave = threadIdx.x >> 6;
    const int lane = threadIdx.x & 63;
    const int quad = lane >> 4;
    const int l16  = lane & 15;
    const int rowbase = blockIdx.x * 128 + wave * 32;

    floatx4 acc[2][8];
#pragma unroll
    for (int r = 0; r < 2; ++r)
#pragma unroll
        for (int c = 0; c < 8; ++c) acc[r][c] = (floatx4){0.f, 0.f, 0.f, 0.f};

    int arow0 = rowbase + l16;      if (arow0 >= N) arow0 = N - 1;
    int arow1 = rowbase + 16 + l16; if (arow1 >= N) arow1 = N - 1;
    const size_t aoff0 = (size_t)arow0 * 128 + quad * 8;
    const size_t aoff1 = (size_t)arow1 * 128 + quad * 8;

#pragma unroll
    for (int kb = 0; kb < 8; ++kb) {
        const unsigned short* Ab = (kb < 4) ? Aggb : Xb;
        const int koff = (kb & 3) * 32;
        short8 a0 = __builtin_bit_cast(short8, *(const uint4*)(Ab + aoff0 + koff));
        short8 a1 = __builtin_bit_cast(short8, *(const uint4*)(Ab + aoff1 + koff));
#pragma unroll
        for (int c = 0; c < 8; ++c) {
            short8 b = __builtin_bit_cast(short8,
                *(const uint4*)(Wt + (size_t)(((c * 8 + kb) * 64 + lane) * 8)));
            acc[0][c] = __builtin_amdgcn_mfma_f32_16x16x32_bf16(a0, b, acc[0][c], 0, 0, 0);
            acc[1][c] = __builtin_amdgcn_mfma_f32_16x16x32_bf16(a1, b, acc[1][c], 0, 0, 0);
        }
    }

    float bcol[8];
#pragma unroll
    for (int c = 0; c < 8; ++c) bcol[c] = bias[c * 16 + l16];
#pragma unroll
    for (int r = 0; r < 2; ++r)
#pragma unroll
        for (int i = 0; i < 4; ++i) {
            int row = rowbase + r * 16 + quad * 4 + i;
            if (row < N) {
#pragma unroll
                for (int c = 0; c < 8; ++c)
                    Hb[(size_t)row * 128 + c * 16 + l16] =
                        f2b(fmaxf(acc[r][c][i] + bcol[c], 0.f));
            }
        }
}

// out = [H1 | H2] @ Wot + b_out (fp32 out, 40 cols via 3 masked tiles).
__global__ __launch_bounds__(256)
void out_gemm_mfma(const unsigned short* __restrict__ H1b,
                   const unsigned short* __restrict__ H2b,
                   const unsigned short* __restrict__ Wot,  // frag-order [3][8][64][8]
                   const float* __restrict__ bo,
                   float* __restrict__ out, int N) {
    const int wave = threadIdx.x >> 6;
    const int lane = threadIdx.x & 63;
    const int quad = lane >> 4;
    const int l16  = lane & 15;
    const int rowbase = blockIdx.x * 128 + wave * 32;

    floatx4 acc[2][3];
#pragma unroll
    for (int r = 0; r < 2; ++r)
#pragma unroll
        for (int c = 0; c < 3; ++c) acc[r][c] = (floatx4){0.f, 0.f, 0.f, 0.f};

    int arow0 = rowbase + l16;      if (arow0 >= N) arow0 = N - 1;
    int arow1 = rowbase + 16 + l16; if (arow1 >= N) arow1 = N - 1;
    const size_t aoff0 = (size_t)arow0 * 128 + quad * 8;
    const size_t aoff1 = (size_t)arow1 * 128 + quad * 8;

#pragma unroll
    for (int kb = 0; kb < 8; ++kb) {
        const unsigned short* Ab = (kb < 4) ? H1b : H2b;
        const int koff = (kb & 3) * 32;
        short8 a0 = __builtin_bit_cast(short8, *(const uint4*)(Ab + aoff0 + koff));
        short8 a1 = __builtin_bit_cast(short8, *(const uint4*)(Ab + aoff1 + koff));
#pragma unroll
        for (int c = 0; c < 3; ++c) {
            short8 b = __builtin_bit_cast(short8,
                *(const uint4*)(Wot + (size_t)(((c * 8 + kb) * 64 + lane) * 8)));
            acc[0][c] = __builtin_amdgcn_mfma_f32_16x16x32_bf16(a0, b, acc[0][c], 0, 0, 0);
            acc[1][c] = __builtin_amdgcn_mfma_f32_16x16x32_bf16(a1, b, acc[1][c], 0, 0, 0);
        }
    }

    float bcol[3];
#pragma unroll
    for (int c = 0; c < 3; ++c) {
        int colc = c * 16 + l16;
        bcol[c] = (colc < 40) ? bo[colc] : 0.f;
    }
#pragma unroll
    for (int r = 0; r < 2; ++r)
#pragma unroll
        for (int i = 0; i < 4; ++i) {
            int row = rowbase + r * 16 + quad * 4 + i;
            if (row < N) {
#pragma unroll
                for (int c = 0; c < 3; ++c) {
                    int colc = c * 16 + l16;
                    if (colc < 40)
                        out[(size_t)row * 40 + colc] = acc[r][c][i] + bcol[c];
                }
            }
        }
}

extern "C" void kernel_launch(void* const* d_in, const int* in_sizes, int n_in,
                              void* d_out, int out_size, void* d_ws, size_t ws_size,
                              hipStream_t stream) {
    const float* x     = (const float*)d_in[0];
    const int*   ei1   = (const int*)d_in[1];
    const int*   ei2   = (const int*)d_in[2];
    const float* wl1   = (const float*)d_in[3];
    const float* wr1   = (const float*)d_in[4];
    const float* b1    = (const float*)d_in[5];
    const float* wl2   = (const float*)d_in[6];
    const float* wr2   = (const float*)d_in[7];
    const float* b2    = (const float*)d_in[8];
    const float* w_out = (const float*)d_in[9];
    const float* b_out = (const float*)d_in[10];

    const int N  = in_sizes[0] / 128;
    const int E  = in_sizes[1] / 2;
    const int nb = (N + 255) >> 8;   // buckets of 256 dst nodes (<= MAXB)

    // ---- workspace (ints): [hist1|gcur1|hist2|gcur2]=2048 | bptr1 | bptr2 |
    //      row_ptr1 | row_ptr2 | part1 | col1 | part2 | col2 | bf16 arrays
    int* hist1    = (int*)d_ws;
    int* gcur1    = hist1 + 512;
    int* hist2    = gcur1 + 512;
    int* gcur2    = hist2 + 512;
    int* bptr1    = gcur2 + 512;
    int* bptr2    = bptr1 + 513;
    int* row_ptr1 = bptr2 + 513;
    int* row_ptr2 = row_ptr1 + (N + 1);
    int* part1    = row_ptr2 + (N + 1);
    int* col1     = part1 + E;
    int* part2    = col1 + E;
    int* col2     = part2 + E;
    size_t int_cnt = (size_t)(2048 + 1026 + 2 * (N + 1)) + (size_t)4 * E;
    int_cnt = (int_cnt + 3) & ~(size_t)3;                 // 16 B align
    unsigned short* xb   = (unsigned short*)((int*)d_ws + int_cnt);
    unsigned short* h1b  = xb  + (size_t)N * 128;
    unsigned short* h2b  = h1b + (size_t)N * 128;
    unsigned short* aggb = h2b + (size_t)N * 128;
    unsigned short* wt1  = aggb + (size_t)N * 128;
    unsigned short* wt2  = wt1 + 32768;
    unsigned short* wot  = wt2 + 32768;

    const long n8         = (long)N * 128 / 8;
    const int prep_blocks = (int)((n8 + 255) / 256);      // covers all prep work
    const int gath_blocks = (int)(((size_t)N * 16 + 255) / 256);
    const int mfma_blocks = (N + 127) / 128;

    prep_all<<<prep_blocks, 256, 0, stream>>>(
        (const float4*)x, (uint4*)xb, n8, wl1, wr1, wl2, wr2, w_out,
        wt1, wt2, wot, hist1);

    bucket_hist2<<<dim3(256, 2), 256, 0, stream>>>(ei1 + E, ei2 + E, hist1, hist2, E, nb);
    bucket_scan2<<<2, 256, 0, stream>>>(hist1, hist2, bptr1, bptr2, nb, E);
    partition_edges2<<<dim3(PBLK, 2), 256, 0, stream>>>(
        ei1, ei2, bptr1, bptr2, gcur1, gcur2, part1, part2, E, nb);
    node_sort2<<<dim3(nb, 2), 256, 0, stream>>>(
        bptr1, bptr2, part1, part2, col1, col2, row_ptr1, row_ptr2, N, E);

    // ---- layer 1
    gather_mean_b16<<<gath_blocks, 256, 0, stream>>>((const uint4*)xb, row_ptr1,
                                                     col1, (uint4*)aggb, N);
    sage_gemm_mfma<<<mfma_blocks, 256, 0, stream>>>(aggb, xb, wt1, b1, h1b, N);
    // ---- layer 2
    gather_mean_b16<<<gath_blocks, 256, 0, stream>>>((const uint4*)h1b, row_ptr2,
                                                     col2, (uint4*)aggb, N);
    sage_gemm_mfma<<<mfma_blocks, 256, 0, stream>>>(aggb, h1b, wt2, b2, h2b, N);

    out_gemm_mfma<<<mfma_blocks, 256, 0, stream>>>(h1b, h2b, wot, b_out,
                                                   (float*)d_out, N);
}